// Round 8
// baseline (190.139 us; speedup 1.0000x reference)
//
#include <hip/hip_runtime.h>
#include <math.h>

#define SDIM 3
#define BDIM 32
#define NPRI 2000
#define LDIM 4
#define DDIM 78
#define NSB (SDIM * BDIM)   // 96

// ws layout:
//   rowsws [2][4] i :  32 B  (last-sb rows only, not zeroed)
//   clsSum [2][2000] f : 16,000 B  (atomic, zeroed via memset)
//   corrws [2][2000] f : 16,000 B  (atomic, zeroed via memset)
//   regacc [2][8]    f :     64 B  (atomic, zeroed via memset)

// ---------------------------------------------------------------------------
// fused cost + greedy assign + reg/iou + matched focal. grid (96, 2),
// block 1024 (16 waves). Cost matrix [4][2000] lives in LDS (32 KB).
// Cost phase: 1 THREAD PER PRIOR, 2 passes. All 39 float2 loads of the
// 312 B row are issued as one batch (R7's 28-VGPR / 4-lane version had
// zero cross-pass MLP -- every pass ate a full memory latency).
// __launch_bounds__(1024,4) raises the VGPR cap to 128; only 192 blocks
// exist on 256 CUs so 1 block/CU residency is the cap anyway.
// Bit-exactness: per-quarter accumulators in identical element order,
// combined (q0+q1)+(q2+q3) == the old shfl_xor tree. No global_load_lds
// (replay-unstable, R2/R5 evidence); no candidate compression (R5/R6).
__global__ __launch_bounds__(1024, 4) void fused_kernel(
    const float* __restrict__ predsA, const float* __restrict__ predsB,
    const float* __restrict__ gt,
    int* __restrict__ rowsws, float* __restrict__ regacc,
    float* __restrict__ corrws, float* __restrict__ clsSum)
{
    const int sb = blockIdx.x, branch = blockIdx.y;
    const float* preds = branch ? predsB : predsA;
    const int bimg = sb % BDIM;
    const int tid = threadIdx.x;
    const int wv = tid >> 6, lane = tid & 63;

    __shared__ float cost[LDIM][NPRI];   // 32,000 B
    __shared__ float tg[36 * 8];         //  1,152 B: [jj][l*2+k]
    __shared__ float geo4[16];           //     64 B: [l][c]
    __shared__ float redv[16];
    __shared__ int   redi[16];
    __shared__ int   rows_lds[LDIM];

    {
        const float* gtb = gt + (size_t)bimg * LDIM * DDIM;
        if (tid < 288) {
            int jj = tid >> 3, t = tid & 7, l = t >> 1, k = t & 1;
            tg[tid] = gtb[l * DDIM + 6 + 2 * jj + k] / 799.0f;
        }
        if (tid < 16) geo4[tid] = gtb[(tid >> 2) * DDIM + 2 + (tid & 3)];
    }
    __syncthreads();

    // ---- cost phase: 1 thread/prior, 2 passes of 1024 ----
    const float* gpb = preds + (size_t)sb * NPRI * DDIM;

    for (int pass = 0; pass < 2; ++pass) {
        const int n = pass * 1024 + tid;
        if (n < NPRI) {
            const float* p = gpb + (size_t)n * DDIM;
            // full row batch: headers + 36 offset float2s (row is 8B aligned)
            float2 hd0 = *(const float2*)(p);
            float2 hd1 = *(const float2*)(p + 2);
            float2 hd2 = *(const float2*)(p + 4);
            float2 ov[36];
#pragma unroll
            for (int q = 0; q < 36; ++q) ov[q] = *(const float2*)(p + 6 + 2 * q);

            // per-quarter, per-target partial sums -- identical element order
            float accq[4][4];
#pragma unroll
            for (int qt = 0; qt < 4; ++qt)
#pragma unroll
                for (int l = 0; l < 4; ++l) accq[qt][l] = 0.f;

#pragma unroll
            for (int qt = 0; qt < 4; ++qt) {
#pragma unroll
                for (int q = 0; q < 9; ++q) {
                    const int jj = qt * 9 + q;
                    float pv0 = ov[jj].x;
                    float pv1 = ov[jj].y;
                    const float4* t4 = (const float4*)(tg + jj * 8);
                    float4 ta = t4[0], tb = t4[1];
                    accq[qt][0] += fabsf(pv0 - ta.x); accq[qt][0] += fabsf(pv1 - ta.y);
                    accq[qt][1] += fabsf(pv0 - ta.z); accq[qt][1] += fabsf(pv1 - ta.w);
                    accq[qt][2] += fabsf(pv0 - tb.x); accq[qt][2] += fabsf(pv1 - tb.y);
                    accq[qt][3] += fabsf(pv0 - tb.z); accq[qt][3] += fabsf(pv1 - tb.w);
                }
            }

            float a = hd0.x, b1 = hd0.y;
            float m = fmaxf(a, b1);
            float ea = expf(a - m), eb = expf(b1 - m);
            float score = eb / (ea + eb);
            float g0 = hd1.x, g1 = hd1.y, g2 = hd2.x, g3 = hd2.y;

#pragma unroll
            for (int l = 0; l < 4; ++l) {
                // same tree as the old shfl_xor combine: (q0+q1)+(q2+q3)
                float offs = (accq[0][l] + accq[1][l]) + (accq[2][l] + accq[3][l]);
                float geo = fabsf(g0 - geo4[l * 4 + 0]) + fabsf(g1 - geo4[l * 4 + 1])
                          + fabsf(g2 - geo4[l * 4 + 2]) + fabsf(g3 - geo4[l * 4 + 3]);
                cost[l][n] = geo + offs / 72.0f - score;
            }

            {
                float lse = m + logf(ea + eb);
                float logpt = a - lse;
                float pt = expf(logpt);
                float om = 1.0f - pt;
                atomicAdd(&clsSum[branch * NPRI + n], -(0.1f * om * om * logpt));
            }
        }
    }
    __syncthreads();

    // ---- greedy argmin (jnp.argmin tie-break: lowest index wins) ----
    for (int l = 0; l < LDIM; ++l) {
        float bv = INFINITY; int bi = 0x7fffffff;
        for (int k = tid; k < NPRI; k += 1024) {
            float v = cost[l][k];
            if (v < bv) { bv = v; bi = k; }
        }
#pragma unroll
        for (int off = 32; off > 0; off >>= 1) {
            float v2 = __shfl_down(bv, off);
            int   i2 = __shfl_down(bi, off);
            if (v2 < bv || (v2 == bv && i2 < bi)) { bv = v2; bi = i2; }
        }
        if (lane == 0) { redv[wv] = bv; redi[wv] = bi; }
        __syncthreads();
        if (tid == 0) {
            float fv = redv[0]; int fi = redi[0];
#pragma unroll
            for (int w = 1; w < 16; ++w)
                if (redv[w] < fv || (redv[w] == fv && redi[w] < fi)) { fv = redv[w]; fi = redi[w]; }
            rows_lds[l] = fi;
            cost[0][fi] = INFINITY; cost[1][fi] = INFINITY;
            cost[2][fi] = INFINITY; cost[3][fi] = INFINITY;
        }
        __syncthreads();
    }
    if (tid < LDIM && sb == NSB - 1) rowsws[branch * LDIM + tid] = rows_lds[tid];

    // ---- regiou + matched focal corr: wave wv (<4) handles target l = wv ----
    if (wv < 4) {
        const int l = wv;
        const int row = rows_lds[l];
        const float* pm = preds + ((size_t)sb * NPRI + row) * DDIM;  // L2-hot
        const float* tgp = gt + ((size_t)bimg * LDIM + l) * DDIM;

        float osum = 0.f, usum = 0.f, rterm = 0.f;
        {
            float rp = pm[6 + lane] * 799.0f;
            float rt = tgp[6 + lane];
            bool inv = (rt < 0.0f) || (rt >= 800.0f);
            float ov = fminf(rp, rt) - fmaxf(rp, rt) + 30.0f;
            float un = fmaxf(rp, rt) - fminf(rp, rt) + 30.0f;
            if (!inv) { osum += ov; usum += un; }
        }
        if (lane < 8) {
            float rp = pm[6 + lane + 64] * 799.0f;
            float rt = tgp[6 + lane + 64];
            bool inv = (rt < 0.0f) || (rt >= 800.0f);
            float ov = fminf(rp, rt) - fmaxf(rp, rt) + 30.0f;
            float un = fmaxf(rp, rt) - fminf(rp, rt) + 30.0f;
            if (!inv) { osum += ov; usum += un; }
        }
        if (lane < 4) {
            const float scv[4] = {71.0f, 799.0f, 180.0f, 71.0f};
            float s = scv[lane];
            float d = pm[2 + lane] * s - tgp[2 + lane] * s;
            float ad = fabsf(d);
            rterm = (ad < 1.0f) ? 0.5f * d * d : ad - 0.5f;
        }
#pragma unroll
        for (int off = 32; off > 0; off >>= 1) {
            osum += __shfl_down(osum, off);
            usum += __shfl_down(usum, off);
            rterm += __shfl_down(rterm, off);
        }
        if (lane == 0) {
            float iou = osum / (usum + 1e-9f);
            atomicAdd(&regacc[branch * 8 + l], (rterm / 4.0f) / 4.0f);
            atomicAdd(&regacc[branch * 8 + 4 + l], (1.0f - iou) / 4.0f);

            // matched focal correction (pos replaces neg for this prior)
            float a = pm[0], b1 = pm[1];
            float m = fmaxf(a, b1);
            float ea = expf(a - m), eb = expf(b1 - m);
            float lse = m + logf(ea + eb);
            float lp0 = a - lse, lp1 = b1 - lse;
            float pt0 = expf(lp0), pt1 = expf(lp1);
            float om0 = 1.0f - pt0, om1 = 1.0f - pt1;
            float neg = -(0.1f * om0 * om0 * lp0);
            float pos = -(0.9f * om1 * om1 * lp1);
            atomicAdd(&corrws[branch * NPRI + row], pos - neg);
        }
    }
}

// ---------------------------------------------------------------------------
// final: inst vectors, exact median via 4-round radix select (O(n)/round),
// weighted sum -> scalar.
__device__ __forceinline__ unsigned mapf(float f) {
    unsigned u = __float_as_uint(f);
    return (u & 0x80000000u) ? ~u : (u | 0x80000000u);
}
__device__ __forceinline__ float unmapf(unsigned u) {
    return (u & 0x80000000u) ? __uint_as_float(u ^ 0x80000000u)
                             : __uint_as_float(~u);
}

__global__ __launch_bounds__(1024) void final_kernel(
    const float* __restrict__ clsSum, const float* __restrict__ corrws,
    const float* __restrict__ regacc, const int* __restrict__ rowsws,
    const float* __restrict__ diff, float* __restrict__ out)
{
    __shared__ float instA[NPRI];
    __shared__ float instB[NPRI];
    __shared__ unsigned keys[NPRI];
    __shared__ unsigned bufA[NPRI];
    __shared__ unsigned bufB[NPRI];
    __shared__ unsigned cnt[256];
    __shared__ unsigned wpre[4];
    __shared__ unsigned selBin, selBefore, outCnt;
    __shared__ int      redc[16];
    __shared__ unsigned redm[16];
    __shared__ float    deltaSh;
    __shared__ float    red[1024];
    const int tid = threadIdx.x;
    const int wv = tid >> 6, lane = tid & 63;

    for (int n = tid; n < NPRI; n += 1024) {
        float ia = (clsSum[n] + corrws[n]) * (2.0f / 96.0f);
        float ib = (clsSum[NPRI + n] + corrws[NPRI + n]) * (2.0f / 96.0f);
#pragma unroll
        for (int l = 0; l < 4; ++l) {
            if (rowsws[l] == n)
                ia += (regacc[l] / 96.0f) * 0.5f + (regacc[4 + l] / 96.0f) * 2.0f;
            if (rowsws[4 + l] == n)
                ib += (regacc[8 + l] / 96.0f) * 0.5f + (regacc[12 + l] / 96.0f) * 2.0f;
        }
        instA[n] = ia; instB[n] = ib;
        keys[n] = mapf(ia - ib);
    }
    __syncthreads();

    // ---- radix select k=999 (0-indexed) over 2000 keys ----
    int curk = 999;
    unsigned prefix = 0;
    unsigned m = NPRI;
    unsigned* src = keys;
    unsigned* dst = bufA;

    for (int r = 0; r < 4; ++r) {
        const int shift = 24 - 8 * r;
        if (tid < 256) cnt[tid] = 0;
        __syncthreads();
        for (unsigned i = tid; i < m; i += 1024)
            atomicAdd(&cnt[(src[i] >> shift) & 255u], 1u);
        __syncthreads();

        unsigned v = 0, inc = 0;
        if (tid < 256) {
            v = cnt[tid]; inc = v;
#pragma unroll
            for (int o = 1; o < 64; o <<= 1) {
                unsigned t = __shfl_up(inc, o);
                if ((tid & 63) >= o) inc += t;
            }
            if ((tid & 63) == 63) wpre[tid >> 6] = inc;
        }
        __syncthreads();
        if (tid < 256) {
            unsigned base = 0;
#pragma unroll
            for (int w = 0; w < 3; ++w) if (w < (tid >> 6)) base += wpre[w];
            unsigned incl = base + inc, excl = incl - v;
            if (v > 0 && (unsigned)curk >= excl && (unsigned)curk < incl) {
                selBin = tid; selBefore = excl;
            }
        }
        __syncthreads();
        const unsigned b = selBin;
        curk -= (int)selBefore;
        prefix |= b << shift;

        if (r < 3) {
            if (tid == 0) outCnt = 0;
            __syncthreads();
            for (unsigned i = tid; i < m; i += 1024) {
                unsigned u = src[i];
                if (((u >> shift) & 255u) == b) {
                    unsigned p = atomicAdd(&outCnt, 1u);
                    dst[p] = u;
                }
            }
            __syncthreads();
            m = outCnt;
            src = dst;
            dst = (dst == bufA) ? bufB : bufA;
        }
    }
    const unsigned v999u = prefix;

    // ---- rank-1000 partner: count <= v999; if <1001, min of keys > v999 ----
    {
        int cle = 0; unsigned mn = 0xffffffffu;
        for (int j = tid; j < NPRI; j += 1024) {
            unsigned u = keys[j];
            cle += (u <= v999u);
            if (u > v999u) mn = min(mn, u);
        }
#pragma unroll
        for (int off = 32; off > 0; off >>= 1) {
            cle += __shfl_down(cle, off);
            mn = min(mn, (unsigned)__shfl_down(mn, off));
        }
        if (lane == 0) { redc[wv] = cle; redm[wv] = mn; }
        __syncthreads();
        if (tid == 0) {
            int c = 0; unsigned m2 = 0xffffffffu;
#pragma unroll
            for (int w = 0; w < 16; ++w) { c += redc[w]; m2 = min(m2, redm[w]); }
            unsigned v1000u = (c >= 1001) ? v999u : m2;
            deltaSh = 0.5f * (unmapf(v999u) + unmapf(v1000u));
        }
        __syncthreads();
    }
    const float delta = deltaSh;

    float acc = 0.0f;
    for (int n = tid; n < NPRI; n += 1024) {
        float dm = (diff[n] + diff[NPRI + n] + diff[2 * NPRI + n]) / 3.0f;
        acc += (1.0f - dm) * (instA[n] - 0.5f * delta)
             + dm * (instB[n] + 0.5f * delta);
    }
    red[tid] = acc;
    __syncthreads();
    for (int s = 512; s > 0; s >>= 1) {
        if (tid < s) red[tid] += red[tid + s];
        __syncthreads();
    }
    if (tid == 0) out[0] = red[0];
}

// ---------------------------------------------------------------------------
extern "C" void kernel_launch(void* const* d_in, const int* in_sizes, int n_in,
                              void* d_out, int out_size, void* d_ws, size_t ws_size,
                              hipStream_t stream)
{
    const float* predsA = (const float*)d_in[0];
    const float* predsB = (const float*)d_in[1];
    const float* gt     = (const float*)d_in[2];
    const float* diff   = (const float*)d_in[3];
    float* out = (float*)d_out;

    int*   rowsws = (int*)d_ws;                           //         8 i
    float* clsSum = (float*)(rowsws + 8);                 //     4,000 f
    float* corrws = clsSum + 2 * NPRI;                    //     4,000 f
    float* regacc = corrws + 2 * NPRI;                    //        16 f

    // zero the atomic accumulators (clsSum, corrws, regacc are contiguous)
    hipMemsetAsync(clsSum, 0, (4 * NPRI + 16) * sizeof(float), stream);

    dim3 g1(NSB, 2);
    fused_kernel<<<g1, 1024, 0, stream>>>(predsA, predsB, gt,
                                          rowsws, regacc, corrws, clsSum);

    final_kernel<<<1, 1024, 0, stream>>>(clsSum, corrws, regacc, rowsws, diff, out);
}

// Round 9
// 165.739 us; speedup vs baseline: 1.1472x; 1.1472x over previous
//
#include <hip/hip_runtime.h>
#include <math.h>

#define SDIM 3
#define BDIM 32
#define NPRI 2000
#define LDIM 4
#define DDIM 78
#define NSB (SDIM * BDIM)   // 96

// ws layout:
//   rowsws [2][4] i :  32 B  (last-sb rows only, not zeroed)
//   clsSum [2][2000] f : 16,000 B  (atomic, zeroed via memset)
//   corrws [2][2000] f : 16,000 B  (atomic, zeroed via memset)
//   regacc [2][8]    f :     64 B  (atomic, zeroed via memset)

// ---------------------------------------------------------------------------
// fused cost + greedy assign + reg/iou + matched focal. grid (96, 2),
// block 1024 (16 waves). Cost matrix [4][2000] in LDS (32 KB).
// Cost phase: 8 passes x 256 priors. Each pass's 79,872 B preds tile is
// staged through LDS via COALESCED float4 stream copies (the preds slab is
// contiguous; rows ignored during staging). T14 split: pass p+1's 5 f4/thread
// are issued into named registers BEFORE pass p's compute and ds_write-
// drained after the barrier -- HBM latency hides under compute.
// Compute is R7's exact 4-lane/prior quad (cache-line-efficient; R8's
// 1-thread/prior touched 64 lines/instr and regressed). Values pass through
// LDS bit-identically -> absmax 0.0 preserved. No global_load_lds
// (replay-unstable, R2/R5); no candidate compression (diverged, R5/R6);
// no big register arrays (R4/R8: compiler won't batch, VALUBusy falls).
__global__ __launch_bounds__(1024, 4) void fused_kernel(
    const float* __restrict__ predsA, const float* __restrict__ predsB,
    const float* __restrict__ gt,
    int* __restrict__ rowsws, float* __restrict__ regacc,
    float* __restrict__ corrws, float* __restrict__ clsSum)
{
    const int sb = blockIdx.x, branch = blockIdx.y;
    const float* preds = branch ? predsB : predsA;
    const int bimg = sb % BDIM;
    const int tid = threadIdx.x;
    const int wv = tid >> 6, lane = tid & 63;

    __shared__ __align__(16) float tile[256 * DDIM];  // 79,872 B
    __shared__ float cost[LDIM][NPRI];   // 32,000 B
    __shared__ float tg[36 * 8];         //  1,152 B: [jj][l*2+k]
    __shared__ float geo4[16];           //     64 B: [l][c]
    __shared__ float redv[16];
    __shared__ int   redi[16];
    __shared__ int   rows_lds[LDIM];

    {
        const float* gtb = gt + (size_t)bimg * LDIM * DDIM;
        if (tid < 288) {
            int jj = tid >> 3, t = tid & 7, l = t >> 1, k = t & 1;
            tg[tid] = gtb[l * DDIM + 6 + 2 * jj + k] / 799.0f;
        }
        if (tid < 16) geo4[tid] = gtb[(tid >> 2) * DDIM + 2 + (tid & 3)];
    }

    // ---- cost phase: 8 passes x 256 priors, LDS-staged, T14 pipelined ----
    // full pass: 4992 f4 (256 rows); last pass (7): 4056 f4 (208 rows).
    const int h = tid & 3;               // offset quarter / target lane
    const float4* gs4 = (const float4*)(preds + (size_t)sb * NPRI * DDIM);
    float4* t4 = (float4*)tile;
    float4 s0, s1, s2, s3, s4;

    // prologue: load + write pass 0 (full)
    {
        const float4* b = gs4;
        s0 = b[tid]; s1 = b[tid + 1024]; s2 = b[tid + 2048]; s3 = b[tid + 3072];
        if (tid < 896) s4 = b[tid + 4096];
        t4[tid] = s0; t4[tid + 1024] = s1; t4[tid + 2048] = s2; t4[tid + 3072] = s3;
        if (tid < 896) t4[tid + 4096] = s4;
    }
    __syncthreads();

    for (int pass = 0; pass < 8; ++pass) {
        const bool haveNext = (pass < 7);
        const bool nextFull = (pass + 1 < 7);
        // issue next tile's global loads early -- in flight during compute
        if (haveNext) {
            const float4* b = gs4 + (size_t)(pass + 1) * 4992;
            s0 = b[tid]; s1 = b[tid + 1024]; s2 = b[tid + 2048];
            if (nextFull) {
                s3 = b[tid + 3072];
                if (tid < 896) s4 = b[tid + 4096];
            } else {
                if (tid < 984) s3 = b[tid + 3072];
            }
        }

        // compute current pass from LDS tile (R7's exact quad arithmetic)
        {
            const int i = tid >> 2;          // prior within tile, 0..255
            const int n = pass * 256 + i;
            if (n < NPRI) {
                const float* pr = &tile[i * DDIM];
                float2 hd0 = *(const float2*)(pr);
                float2 hd1 = *(const float2*)(pr + 2);
                float2 hd2 = *(const float2*)(pr + 4);
                const float2* pb = (const float2*)(pr + 6 + h * 18);
                float2 ov[9];
#pragma unroll
                for (int q = 0; q < 9; ++q) ov[q] = pb[q];

                float offs0 = 0.f, offs1 = 0.f, offs2 = 0.f, offs3 = 0.f;
#pragma unroll
                for (int q = 0; q < 9; ++q) {
                    float pv0 = ov[q].x;
                    float pv1 = ov[q].y;
                    const float4* tt4 = (const float4*)(tg + (h * 9 + q) * 8);
                    float4 ta = tt4[0], tb = tt4[1];
                    offs0 += fabsf(pv0 - ta.x); offs0 += fabsf(pv1 - ta.y);
                    offs1 += fabsf(pv0 - ta.z); offs1 += fabsf(pv1 - ta.w);
                    offs2 += fabsf(pv0 - tb.x); offs2 += fabsf(pv1 - tb.y);
                    offs3 += fabsf(pv0 - tb.z); offs3 += fabsf(pv1 - tb.w);
                }
                // combine quarters within the 4-lane group
                offs0 += __shfl_xor(offs0, 1); offs1 += __shfl_xor(offs1, 1);
                offs2 += __shfl_xor(offs2, 1); offs3 += __shfl_xor(offs3, 1);
                offs0 += __shfl_xor(offs0, 2); offs1 += __shfl_xor(offs1, 2);
                offs2 += __shfl_xor(offs2, 2); offs3 += __shfl_xor(offs3, 2);

                float a = hd0.x, b1 = hd0.y;
                float m = fmaxf(a, b1);
                float ea = expf(a - m), eb = expf(b1 - m);
                float score = eb / (ea + eb);
                float g0 = hd1.x, g1 = hd1.y, g2 = hd2.x, g3 = hd2.y;

                // static select (no runtime-indexed array -> no scratch)
                float mo01 = (h & 1) ? offs1 : offs0;
                float mo23 = (h & 1) ? offs3 : offs2;
                float myoffs = (h & 2) ? mo23 : mo01;

                float geo = fabsf(g0 - geo4[h * 4 + 0]) + fabsf(g1 - geo4[h * 4 + 1])
                          + fabsf(g2 - geo4[h * 4 + 2]) + fabsf(g3 - geo4[h * 4 + 3]);
                cost[h][n] = geo + myoffs / 72.0f - score;

                if (h == 0) {
                    float lse = m + logf(ea + eb);
                    float logpt = a - lse;
                    float pt = expf(logpt);
                    float om = 1.0f - pt;
                    atomicAdd(&clsSum[branch * NPRI + n], -(0.1f * om * om * logpt));
                }
            }
        }
        __syncthreads();                     // all tile reads done
        // drain staged registers into the tile for the next pass
        if (haveNext) {
            t4[tid] = s0; t4[tid + 1024] = s1; t4[tid + 2048] = s2;
            if (nextFull) {
                t4[tid + 3072] = s3;
                if (tid < 896) t4[tid + 4096] = s4;
            } else {
                if (tid < 984) t4[tid + 3072] = s3;
            }
            __syncthreads();                 // tile ready
        }
    }
    __syncthreads();

    // ---- greedy argmin (jnp.argmin tie-break: lowest index wins) ----
    for (int l = 0; l < LDIM; ++l) {
        float bv = INFINITY; int bi = 0x7fffffff;
        for (int k = tid; k < NPRI; k += 1024) {
            float v = cost[l][k];
            if (v < bv) { bv = v; bi = k; }
        }
#pragma unroll
        for (int off = 32; off > 0; off >>= 1) {
            float v2 = __shfl_down(bv, off);
            int   i2 = __shfl_down(bi, off);
            if (v2 < bv || (v2 == bv && i2 < bi)) { bv = v2; bi = i2; }
        }
        if (lane == 0) { redv[wv] = bv; redi[wv] = bi; }
        __syncthreads();
        if (tid == 0) {
            float fv = redv[0]; int fi = redi[0];
#pragma unroll
            for (int w = 1; w < 16; ++w)
                if (redv[w] < fv || (redv[w] == fv && redi[w] < fi)) { fv = redv[w]; fi = redi[w]; }
            rows_lds[l] = fi;
            cost[0][fi] = INFINITY; cost[1][fi] = INFINITY;
            cost[2][fi] = INFINITY; cost[3][fi] = INFINITY;
        }
        __syncthreads();
    }
    if (tid < LDIM && sb == NSB - 1) rowsws[branch * LDIM + tid] = rows_lds[tid];

    // ---- regiou + matched focal corr: wave wv (<4) handles target l = wv ----
    if (wv < 4) {
        const int l = wv;
        const int row = rows_lds[l];
        const float* pm = preds + ((size_t)sb * NPRI + row) * DDIM;  // L2-hot
        const float* tgp = gt + ((size_t)bimg * LDIM + l) * DDIM;

        float osum = 0.f, usum = 0.f, rterm = 0.f;
        {
            float rp = pm[6 + lane] * 799.0f;
            float rt = tgp[6 + lane];
            bool inv = (rt < 0.0f) || (rt >= 800.0f);
            float ov = fminf(rp, rt) - fmaxf(rp, rt) + 30.0f;
            float un = fmaxf(rp, rt) - fminf(rp, rt) + 30.0f;
            if (!inv) { osum += ov; usum += un; }
        }
        if (lane < 8) {
            float rp = pm[6 + lane + 64] * 799.0f;
            float rt = tgp[6 + lane + 64];
            bool inv = (rt < 0.0f) || (rt >= 800.0f);
            float ov = fminf(rp, rt) - fmaxf(rp, rt) + 30.0f;
            float un = fmaxf(rp, rt) - fminf(rp, rt) + 30.0f;
            if (!inv) { osum += ov; usum += un; }
        }
        if (lane < 4) {
            const float scv[4] = {71.0f, 799.0f, 180.0f, 71.0f};
            float s = scv[lane];
            float d = pm[2 + lane] * s - tgp[2 + lane] * s;
            float ad = fabsf(d);
            rterm = (ad < 1.0f) ? 0.5f * d * d : ad - 0.5f;
        }
#pragma unroll
        for (int off = 32; off > 0; off >>= 1) {
            osum += __shfl_down(osum, off);
            usum += __shfl_down(usum, off);
            rterm += __shfl_down(rterm, off);
        }
        if (lane == 0) {
            float iou = osum / (usum + 1e-9f);
            atomicAdd(&regacc[branch * 8 + l], (rterm / 4.0f) / 4.0f);
            atomicAdd(&regacc[branch * 8 + 4 + l], (1.0f - iou) / 4.0f);

            // matched focal correction (pos replaces neg for this prior)
            float a = pm[0], b1 = pm[1];
            float m = fmaxf(a, b1);
            float ea = expf(a - m), eb = expf(b1 - m);
            float lse = m + logf(ea + eb);
            float lp0 = a - lse, lp1 = b1 - lse;
            float pt0 = expf(lp0), pt1 = expf(lp1);
            float om0 = 1.0f - pt0, om1 = 1.0f - pt1;
            float neg = -(0.1f * om0 * om0 * lp0);
            float pos = -(0.9f * om1 * om1 * lp1);
            atomicAdd(&corrws[branch * NPRI + row], pos - neg);
        }
    }
}

// ---------------------------------------------------------------------------
// final: inst vectors, exact median via 4-round radix select (O(n)/round),
// weighted sum -> scalar.
__device__ __forceinline__ unsigned mapf(float f) {
    unsigned u = __float_as_uint(f);
    return (u & 0x80000000u) ? ~u : (u | 0x80000000u);
}
__device__ __forceinline__ float unmapf(unsigned u) {
    return (u & 0x80000000u) ? __uint_as_float(u ^ 0x80000000u)
                             : __uint_as_float(~u);
}

__global__ __launch_bounds__(1024) void final_kernel(
    const float* __restrict__ clsSum, const float* __restrict__ corrws,
    const float* __restrict__ regacc, const int* __restrict__ rowsws,
    const float* __restrict__ diff, float* __restrict__ out)
{
    __shared__ float instA[NPRI];
    __shared__ float instB[NPRI];
    __shared__ unsigned keys[NPRI];
    __shared__ unsigned bufA[NPRI];
    __shared__ unsigned bufB[NPRI];
    __shared__ unsigned cnt[256];
    __shared__ unsigned wpre[4];
    __shared__ unsigned selBin, selBefore, outCnt;
    __shared__ int      redc[16];
    __shared__ unsigned redm[16];
    __shared__ float    deltaSh;
    __shared__ float    red[1024];
    const int tid = threadIdx.x;
    const int wv = tid >> 6, lane = tid & 63;

    for (int n = tid; n < NPRI; n += 1024) {
        float ia = (clsSum[n] + corrws[n]) * (2.0f / 96.0f);
        float ib = (clsSum[NPRI + n] + corrws[NPRI + n]) * (2.0f / 96.0f);
#pragma unroll
        for (int l = 0; l < 4; ++l) {
            if (rowsws[l] == n)
                ia += (regacc[l] / 96.0f) * 0.5f + (regacc[4 + l] / 96.0f) * 2.0f;
            if (rowsws[4 + l] == n)
                ib += (regacc[8 + l] / 96.0f) * 0.5f + (regacc[12 + l] / 96.0f) * 2.0f;
        }
        instA[n] = ia; instB[n] = ib;
        keys[n] = mapf(ia - ib);
    }
    __syncthreads();

    // ---- radix select k=999 (0-indexed) over 2000 keys ----
    int curk = 999;
    unsigned prefix = 0;
    unsigned m = NPRI;
    unsigned* src = keys;
    unsigned* dst = bufA;

    for (int r = 0; r < 4; ++r) {
        const int shift = 24 - 8 * r;
        if (tid < 256) cnt[tid] = 0;
        __syncthreads();
        for (unsigned i = tid; i < m; i += 1024)
            atomicAdd(&cnt[(src[i] >> shift) & 255u], 1u);
        __syncthreads();

        unsigned v = 0, inc = 0;
        if (tid < 256) {
            v = cnt[tid]; inc = v;
#pragma unroll
            for (int o = 1; o < 64; o <<= 1) {
                unsigned t = __shfl_up(inc, o);
                if ((tid & 63) >= o) inc += t;
            }
            if ((tid & 63) == 63) wpre[tid >> 6] = inc;
        }
        __syncthreads();
        if (tid < 256) {
            unsigned base = 0;
#pragma unroll
            for (int w = 0; w < 3; ++w) if (w < (tid >> 6)) base += wpre[w];
            unsigned incl = base + inc, excl = incl - v;
            if (v > 0 && (unsigned)curk >= excl && (unsigned)curk < incl) {
                selBin = tid; selBefore = excl;
            }
        }
        __syncthreads();
        const unsigned b = selBin;
        curk -= (int)selBefore;
        prefix |= b << shift;

        if (r < 3) {
            if (tid == 0) outCnt = 0;
            __syncthreads();
            for (unsigned i = tid; i < m; i += 1024) {
                unsigned u = src[i];
                if (((u >> shift) & 255u) == b) {
                    unsigned p = atomicAdd(&outCnt, 1u);
                    dst[p] = u;
                }
            }
            __syncthreads();
            m = outCnt;
            src = dst;
            dst = (dst == bufA) ? bufB : bufA;
        }
    }
    const unsigned v999u = prefix;

    // ---- rank-1000 partner: count <= v999; if <1001, min of keys > v999 ----
    {
        int cle = 0; unsigned mn = 0xffffffffu;
        for (int j = tid; j < NPRI; j += 1024) {
            unsigned u = keys[j];
            cle += (u <= v999u);
            if (u > v999u) mn = min(mn, u);
        }
#pragma unroll
        for (int off = 32; off > 0; off >>= 1) {
            cle += __shfl_down(cle, off);
            mn = min(mn, (unsigned)__shfl_down(mn, off));
        }
        if (lane == 0) { redc[wv] = cle; redm[wv] = mn; }
        __syncthreads();
        if (tid == 0) {
            int c = 0; unsigned m2 = 0xffffffffu;
#pragma unroll
            for (int w = 0; w < 16; ++w) { c += redc[w]; m2 = min(m2, redm[w]); }
            unsigned v1000u = (c >= 1001) ? v999u : m2;
            deltaSh = 0.5f * (unmapf(v999u) + unmapf(v1000u));
        }
        __syncthreads();
    }
    const float delta = deltaSh;

    float acc = 0.0f;
    for (int n = tid; n < NPRI; n += 1024) {
        float dm = (diff[n] + diff[NPRI + n] + diff[2 * NPRI + n]) / 3.0f;
        acc += (1.0f - dm) * (instA[n] - 0.5f * delta)
             + dm * (instB[n] + 0.5f * delta);
    }
    red[tid] = acc;
    __syncthreads();
    for (int s = 512; s > 0; s >>= 1) {
        if (tid < s) red[tid] += red[tid + s];
        __syncthreads();
    }
    if (tid == 0) out[0] = red[0];
}

// ---------------------------------------------------------------------------
extern "C" void kernel_launch(void* const* d_in, const int* in_sizes, int n_in,
                              void* d_out, int out_size, void* d_ws, size_t ws_size,
                              hipStream_t stream)
{
    const float* predsA = (const float*)d_in[0];
    const float* predsB = (const float*)d_in[1];
    const float* gt     = (const float*)d_in[2];
    const float* diff   = (const float*)d_in[3];
    float* out = (float*)d_out;

    int*   rowsws = (int*)d_ws;                           //         8 i
    float* clsSum = (float*)(rowsws + 8);                 //     4,000 f
    float* corrws = clsSum + 2 * NPRI;                    //     4,000 f
    float* regacc = corrws + 2 * NPRI;                    //        16 f

    // zero the atomic accumulators (clsSum, corrws, regacc are contiguous)
    hipMemsetAsync(clsSum, 0, (4 * NPRI + 16) * sizeof(float), stream);

    dim3 g1(NSB, 2);
    fused_kernel<<<g1, 1024, 0, stream>>>(predsA, predsB, gt,
                                          rowsws, regacc, corrws, clsSum);

    final_kernel<<<1, 1024, 0, stream>>>(clsSum, corrws, regacc, rowsws, diff, out);
}

// Round 10
// 163.414 us; speedup vs baseline: 1.1635x; 1.0142x over previous
//
#include <hip/hip_runtime.h>
#include <math.h>

#define SDIM 3
#define BDIM 32
#define NPRI 2000
#define LDIM 4
#define DDIM 78
#define NSB (SDIM * BDIM)   // 96

// ws layout:
//   rowsws [2][4] i :  32 B  (last-sb rows only, not zeroed)
//   clsSum [2][2000] f : 16,000 B  (atomic, zeroed via memset)
//   corrws [2][2000] f : 16,000 B  (atomic, zeroed via memset)
//   regacc [2][8]    f :     64 B  (atomic, zeroed via memset)

// ---------------------------------------------------------------------------
// fused cost + greedy assign + reg/iou + matched focal. grid (96, 2),
// block 1024 (16 waves). Cost matrix [4][2000] in LDS.
// R10 change vs R9: clsSum atomics DEFERRED out of the pass loop. The
// per-prior focal value goes to an LDS stash (no vmcnt), and the 96-way
// same-address contended atomics are issued only after the greedy phase --
// past the last barrier -- so no s_waitcnt vmcnt(0) ever waits on their
// ack. Theory: atomics share the vmcnt counter with loads; every barrier
// (and every rolling vmcnt(N) wait) stalled on contended cross-XCD atomic
// completion, which is why HBM-resident and L3-resident runs both took
// ~55us (R0/R1/R9 evidence). Everything else identical to R9.
__global__ __launch_bounds__(1024, 4) void fused_kernel(
    const float* __restrict__ predsA, const float* __restrict__ predsB,
    const float* __restrict__ gt,
    int* __restrict__ rowsws, float* __restrict__ regacc,
    float* __restrict__ corrws, float* __restrict__ clsSum)
{
    const int sb = blockIdx.x, branch = blockIdx.y;
    const float* preds = branch ? predsB : predsA;
    const int bimg = sb % BDIM;
    const int tid = threadIdx.x;
    const int wv = tid >> 6, lane = tid & 63;

    __shared__ __align__(16) float tile[256 * DDIM];  // 79,872 B
    __shared__ float cost[LDIM][NPRI];   // 32,000 B
    __shared__ float fstash[2048];       //  8,192 B: [pass*256 + i]
    __shared__ float tg[36 * 8];         //  1,152 B: [jj][l*2+k]
    __shared__ float geo4[16];           //     64 B: [l][c]
    __shared__ float redv[16];
    __shared__ int   redi[16];
    __shared__ int   rows_lds[LDIM];

    {
        const float* gtb = gt + (size_t)bimg * LDIM * DDIM;
        if (tid < 288) {
            int jj = tid >> 3, t = tid & 7, l = t >> 1, k = t & 1;
            tg[tid] = gtb[l * DDIM + 6 + 2 * jj + k] / 799.0f;
        }
        if (tid < 16) geo4[tid] = gtb[(tid >> 2) * DDIM + 2 + (tid & 3)];
    }

    // ---- cost phase: 8 passes x 256 priors, LDS-staged, T14 pipelined ----
    // full pass: 4992 f4 (256 rows); last pass (7): 4056 f4 (208 rows).
    const int h = tid & 3;               // offset quarter / target lane
    const float4* gs4 = (const float4*)(preds + (size_t)sb * NPRI * DDIM);
    float4* t4 = (float4*)tile;
    float4 s0, s1, s2, s3, s4;

    // prologue: load + write pass 0 (full)
    {
        const float4* b = gs4;
        s0 = b[tid]; s1 = b[tid + 1024]; s2 = b[tid + 2048]; s3 = b[tid + 3072];
        if (tid < 896) s4 = b[tid + 4096];
        t4[tid] = s0; t4[tid + 1024] = s1; t4[tid + 2048] = s2; t4[tid + 3072] = s3;
        if (tid < 896) t4[tid + 4096] = s4;
    }
    __syncthreads();

    for (int pass = 0; pass < 8; ++pass) {
        const bool haveNext = (pass < 7);
        const bool nextFull = (pass + 1 < 7);
        // issue next tile's global loads early -- in flight during compute
        if (haveNext) {
            const float4* b = gs4 + (size_t)(pass + 1) * 4992;
            s0 = b[tid]; s1 = b[tid + 1024]; s2 = b[tid + 2048];
            if (nextFull) {
                s3 = b[tid + 3072];
                if (tid < 896) s4 = b[tid + 4096];
            } else {
                if (tid < 984) s3 = b[tid + 3072];
            }
        }

        // compute current pass from LDS tile (R7's exact quad arithmetic)
        {
            const int i = tid >> 2;          // prior within tile, 0..255
            const int n = pass * 256 + i;
            if (n < NPRI) {
                const float* pr = &tile[i * DDIM];
                float2 hd0 = *(const float2*)(pr);
                float2 hd1 = *(const float2*)(pr + 2);
                float2 hd2 = *(const float2*)(pr + 4);
                const float2* pb = (const float2*)(pr + 6 + h * 18);
                float2 ov[9];
#pragma unroll
                for (int q = 0; q < 9; ++q) ov[q] = pb[q];

                float offs0 = 0.f, offs1 = 0.f, offs2 = 0.f, offs3 = 0.f;
#pragma unroll
                for (int q = 0; q < 9; ++q) {
                    float pv0 = ov[q].x;
                    float pv1 = ov[q].y;
                    const float4* tt4 = (const float4*)(tg + (h * 9 + q) * 8);
                    float4 ta = tt4[0], tb = tt4[1];
                    offs0 += fabsf(pv0 - ta.x); offs0 += fabsf(pv1 - ta.y);
                    offs1 += fabsf(pv0 - ta.z); offs1 += fabsf(pv1 - ta.w);
                    offs2 += fabsf(pv0 - tb.x); offs2 += fabsf(pv1 - tb.y);
                    offs3 += fabsf(pv0 - tb.z); offs3 += fabsf(pv1 - tb.w);
                }
                // combine quarters within the 4-lane group
                offs0 += __shfl_xor(offs0, 1); offs1 += __shfl_xor(offs1, 1);
                offs2 += __shfl_xor(offs2, 1); offs3 += __shfl_xor(offs3, 1);
                offs0 += __shfl_xor(offs0, 2); offs1 += __shfl_xor(offs1, 2);
                offs2 += __shfl_xor(offs2, 2); offs3 += __shfl_xor(offs3, 2);

                float a = hd0.x, b1 = hd0.y;
                float m = fmaxf(a, b1);
                float ea = expf(a - m), eb = expf(b1 - m);
                float score = eb / (ea + eb);
                float g0 = hd1.x, g1 = hd1.y, g2 = hd2.x, g3 = hd2.y;

                // static select (no runtime-indexed array -> no scratch)
                float mo01 = (h & 1) ? offs1 : offs0;
                float mo23 = (h & 1) ? offs3 : offs2;
                float myoffs = (h & 2) ? mo23 : mo01;

                float geo = fabsf(g0 - geo4[h * 4 + 0]) + fabsf(g1 - geo4[h * 4 + 1])
                          + fabsf(g2 - geo4[h * 4 + 2]) + fabsf(g3 - geo4[h * 4 + 3]);
                cost[h][n] = geo + myoffs / 72.0f - score;

                if (h == 0) {
                    float lse = m + logf(ea + eb);
                    float logpt = a - lse;
                    float pt = expf(logpt);
                    float om = 1.0f - pt;
                    fstash[n] = -(0.1f * om * om * logpt);   // LDS, no vmcnt
                }
            }
        }
        __syncthreads();                     // all tile reads done
        // drain staged registers into the tile for the next pass
        if (haveNext) {
            t4[tid] = s0; t4[tid + 1024] = s1; t4[tid + 2048] = s2;
            if (nextFull) {
                t4[tid + 3072] = s3;
                if (tid < 896) t4[tid + 4096] = s4;
            } else {
                if (tid < 984) t4[tid + 3072] = s3;
            }
            __syncthreads();                 // tile ready
        }
    }
    __syncthreads();

    // ---- greedy argmin (jnp.argmin tie-break: lowest index wins) ----
    for (int l = 0; l < LDIM; ++l) {
        float bv = INFINITY; int bi = 0x7fffffff;
        for (int k = tid; k < NPRI; k += 1024) {
            float v = cost[l][k];
            if (v < bv) { bv = v; bi = k; }
        }
#pragma unroll
        for (int off = 32; off > 0; off >>= 1) {
            float v2 = __shfl_down(bv, off);
            int   i2 = __shfl_down(bi, off);
            if (v2 < bv || (v2 == bv && i2 < bi)) { bv = v2; bi = i2; }
        }
        if (lane == 0) { redv[wv] = bv; redi[wv] = bi; }
        __syncthreads();
        if (tid == 0) {
            float fv = redv[0]; int fi = redi[0];
#pragma unroll
            for (int w = 1; w < 16; ++w)
                if (redv[w] < fv || (redv[w] == fv && redi[w] < fi)) { fv = redv[w]; fi = redi[w]; }
            rows_lds[l] = fi;
            cost[0][fi] = INFINITY; cost[1][fi] = INFINITY;
            cost[2][fi] = INFINITY; cost[3][fi] = INFINITY;
        }
        __syncthreads();
    }
    if (tid < LDIM && sb == NSB - 1) rowsws[branch * LDIM + tid] = rows_lds[tid];

    // ---- deferred clsSum atomics: past the last barrier, nothing waits ----
    if (h == 0) {
        const int i = tid >> 2;              // 0..255
#pragma unroll
        for (int pass = 0; pass < 8; ++pass) {
            const int n = pass * 256 + i;
            if (n < NPRI)
                atomicAdd(&clsSum[branch * NPRI + n], fstash[n]);
        }
    }

    // ---- regiou + matched focal corr: wave wv (<4) handles target l = wv ----
    if (wv < 4) {
        const int l = wv;
        const int row = rows_lds[l];
        const float* pm = preds + ((size_t)sb * NPRI + row) * DDIM;  // L2-hot
        const float* tgp = gt + ((size_t)bimg * LDIM + l) * DDIM;

        float osum = 0.f, usum = 0.f, rterm = 0.f;
        {
            float rp = pm[6 + lane] * 799.0f;
            float rt = tgp[6 + lane];
            bool inv = (rt < 0.0f) || (rt >= 800.0f);
            float ov = fminf(rp, rt) - fmaxf(rp, rt) + 30.0f;
            float un = fmaxf(rp, rt) - fminf(rp, rt) + 30.0f;
            if (!inv) { osum += ov; usum += un; }
        }
        if (lane < 8) {
            float rp = pm[6 + lane + 64] * 799.0f;
            float rt = tgp[6 + lane + 64];
            bool inv = (rt < 0.0f) || (rt >= 800.0f);
            float ov = fminf(rp, rt) - fmaxf(rp, rt) + 30.0f;
            float un = fmaxf(rp, rt) - fminf(rp, rt) + 30.0f;
            if (!inv) { osum += ov; usum += un; }
        }
        if (lane < 4) {
            const float scv[4] = {71.0f, 799.0f, 180.0f, 71.0f};
            float s = scv[lane];
            float d = pm[2 + lane] * s - tgp[2 + lane] * s;
            float ad = fabsf(d);
            rterm = (ad < 1.0f) ? 0.5f * d * d : ad - 0.5f;
        }
#pragma unroll
        for (int off = 32; off > 0; off >>= 1) {
            osum += __shfl_down(osum, off);
            usum += __shfl_down(usum, off);
            rterm += __shfl_down(rterm, off);
        }
        if (lane == 0) {
            float iou = osum / (usum + 1e-9f);
            atomicAdd(&regacc[branch * 8 + l], (rterm / 4.0f) / 4.0f);
            atomicAdd(&regacc[branch * 8 + 4 + l], (1.0f - iou) / 4.0f);

            // matched focal correction (pos replaces neg for this prior)
            float a = pm[0], b1 = pm[1];
            float m = fmaxf(a, b1);
            float ea = expf(a - m), eb = expf(b1 - m);
            float lse = m + logf(ea + eb);
            float lp0 = a - lse, lp1 = b1 - lse;
            float pt0 = expf(lp0), pt1 = expf(lp1);
            float om0 = 1.0f - pt0, om1 = 1.0f - pt1;
            float neg = -(0.1f * om0 * om0 * lp0);
            float pos = -(0.9f * om1 * om1 * lp1);
            atomicAdd(&corrws[branch * NPRI + row], pos - neg);
        }
    }
}

// ---------------------------------------------------------------------------
// final: inst vectors, exact median via 4-round radix select (O(n)/round),
// weighted sum -> scalar.
__device__ __forceinline__ unsigned mapf(float f) {
    unsigned u = __float_as_uint(f);
    return (u & 0x80000000u) ? ~u : (u | 0x80000000u);
}
__device__ __forceinline__ float unmapf(unsigned u) {
    return (u & 0x80000000u) ? __uint_as_float(u ^ 0x80000000u)
                             : __uint_as_float(~u);
}

__global__ __launch_bounds__(1024) void final_kernel(
    const float* __restrict__ clsSum, const float* __restrict__ corrws,
    const float* __restrict__ regacc, const int* __restrict__ rowsws,
    const float* __restrict__ diff, float* __restrict__ out)
{
    __shared__ float instA[NPRI];
    __shared__ float instB[NPRI];
    __shared__ unsigned keys[NPRI];
    __shared__ unsigned bufA[NPRI];
    __shared__ unsigned bufB[NPRI];
    __shared__ unsigned cnt[256];
    __shared__ unsigned wpre[4];
    __shared__ unsigned selBin, selBefore, outCnt;
    __shared__ int      redc[16];
    __shared__ unsigned redm[16];
    __shared__ float    deltaSh;
    __shared__ float    red[1024];
    const int tid = threadIdx.x;
    const int wv = tid >> 6, lane = tid & 63;

    for (int n = tid; n < NPRI; n += 1024) {
        float ia = (clsSum[n] + corrws[n]) * (2.0f / 96.0f);
        float ib = (clsSum[NPRI + n] + corrws[NPRI + n]) * (2.0f / 96.0f);
#pragma unroll
        for (int l = 0; l < 4; ++l) {
            if (rowsws[l] == n)
                ia += (regacc[l] / 96.0f) * 0.5f + (regacc[4 + l] / 96.0f) * 2.0f;
            if (rowsws[4 + l] == n)
                ib += (regacc[8 + l] / 96.0f) * 0.5f + (regacc[12 + l] / 96.0f) * 2.0f;
        }
        instA[n] = ia; instB[n] = ib;
        keys[n] = mapf(ia - ib);
    }
    __syncthreads();

    // ---- radix select k=999 (0-indexed) over 2000 keys ----
    int curk = 999;
    unsigned prefix = 0;
    unsigned m = NPRI;
    unsigned* src = keys;
    unsigned* dst = bufA;

    for (int r = 0; r < 4; ++r) {
        const int shift = 24 - 8 * r;
        if (tid < 256) cnt[tid] = 0;
        __syncthreads();
        for (unsigned i = tid; i < m; i += 1024)
            atomicAdd(&cnt[(src[i] >> shift) & 255u], 1u);
        __syncthreads();

        unsigned v = 0, inc = 0;
        if (tid < 256) {
            v = cnt[tid]; inc = v;
#pragma unroll
            for (int o = 1; o < 64; o <<= 1) {
                unsigned t = __shfl_up(inc, o);
                if ((tid & 63) >= o) inc += t;
            }
            if ((tid & 63) == 63) wpre[tid >> 6] = inc;
        }
        __syncthreads();
        if (tid < 256) {
            unsigned base = 0;
#pragma unroll
            for (int w = 0; w < 3; ++w) if (w < (tid >> 6)) base += wpre[w];
            unsigned incl = base + inc, excl = incl - v;
            if (v > 0 && (unsigned)curk >= excl && (unsigned)curk < incl) {
                selBin = tid; selBefore = excl;
            }
        }
        __syncthreads();
        const unsigned b = selBin;
        curk -= (int)selBefore;
        prefix |= b << shift;

        if (r < 3) {
            if (tid == 0) outCnt = 0;
            __syncthreads();
            for (unsigned i = tid; i < m; i += 1024) {
                unsigned u = src[i];
                if (((u >> shift) & 255u) == b) {
                    unsigned p = atomicAdd(&outCnt, 1u);
                    dst[p] = u;
                }
            }
            __syncthreads();
            m = outCnt;
            src = dst;
            dst = (dst == bufA) ? bufB : bufA;
        }
    }
    const unsigned v999u = prefix;

    // ---- rank-1000 partner: count <= v999; if <1001, min of keys > v999 ----
    {
        int cle = 0; unsigned mn = 0xffffffffu;
        for (int j = tid; j < NPRI; j += 1024) {
            unsigned u = keys[j];
            cle += (u <= v999u);
            if (u > v999u) mn = min(mn, u);
        }
#pragma unroll
        for (int off = 32; off > 0; off >>= 1) {
            cle += __shfl_down(cle, off);
            mn = min(mn, (unsigned)__shfl_down(mn, off));
        }
        if (lane == 0) { redc[wv] = cle; redm[wv] = mn; }
        __syncthreads();
        if (tid == 0) {
            int c = 0; unsigned m2 = 0xffffffffu;
#pragma unroll
            for (int w = 0; w < 16; ++w) { c += redc[w]; m2 = min(m2, redm[w]); }
            unsigned v1000u = (c >= 1001) ? v999u : m2;
            deltaSh = 0.5f * (unmapf(v999u) + unmapf(v1000u));
        }
        __syncthreads();
    }
    const float delta = deltaSh;

    float acc = 0.0f;
    for (int n = tid; n < NPRI; n += 1024) {
        float dm = (diff[n] + diff[NPRI + n] + diff[2 * NPRI + n]) / 3.0f;
        acc += (1.0f - dm) * (instA[n] - 0.5f * delta)
             + dm * (instB[n] + 0.5f * delta);
    }
    red[tid] = acc;
    __syncthreads();
    for (int s = 512; s > 0; s >>= 1) {
        if (tid < s) red[tid] += red[tid + s];
        __syncthreads();
    }
    if (tid == 0) out[0] = red[0];
}

// ---------------------------------------------------------------------------
extern "C" void kernel_launch(void* const* d_in, const int* in_sizes, int n_in,
                              void* d_out, int out_size, void* d_ws, size_t ws_size,
                              hipStream_t stream)
{
    const float* predsA = (const float*)d_in[0];
    const float* predsB = (const float*)d_in[1];
    const float* gt     = (const float*)d_in[2];
    const float* diff   = (const float*)d_in[3];
    float* out = (float*)d_out;

    int*   rowsws = (int*)d_ws;                           //         8 i
    float* clsSum = (float*)(rowsws + 8);                 //     4,000 f
    float* corrws = clsSum + 2 * NPRI;                    //     4,000 f
    float* regacc = corrws + 2 * NPRI;                    //        16 f

    // zero the atomic accumulators (clsSum, corrws, regacc are contiguous)
    hipMemsetAsync(clsSum, 0, (4 * NPRI + 16) * sizeof(float), stream);

    dim3 g1(NSB, 2);
    fused_kernel<<<g1, 1024, 0, stream>>>(predsA, predsB, gt,
                                          rowsws, regacc, corrws, clsSum);

    final_kernel<<<1, 1024, 0, stream>>>(clsSum, corrws, regacc, rowsws, diff, out);
}